// Round 1
// baseline (355.755 us; speedup 1.0000x reference)
//
#include <hip/hip_runtime.h>
#include <cstdint>

#define D_CH 128
#define T_LEN 1024
#define ROWLEN 384
#define NROWS (128 * 1024)
#define TILE 64
#define NCHUNK (NROWS / TILE)   // 2048
#define KSTRIDE 136             // padded f16 row stride (bank-conflict-free)

typedef __attribute__((ext_vector_type(8))) _Float16 f16x8;
typedef __attribute__((ext_vector_type(4))) _Float16 f16x4;
typedef __attribute__((ext_vector_type(4))) float f32x4;

// Kernel A: per-(b,d) mean over T  +  kernel matrix -> f16 transposed (Kt[n][k])
__global__ __launch_bounds__(256) void prep_kernel(const float* __restrict__ x,
                                                   const float* __restrict__ Kmat,
                                                   float* __restrict__ meang,
                                                   _Float16* __restrict__ Ktg) {
  int bid = blockIdx.x;            // 256 blocks: (b, half-of-D)
  int b = bid >> 1, h = bid & 1;
  int tid = threadIdx.x;
  int li = tid & 15, tt = tid >> 4;      // 16 d-groups x 16 t-slices
  int d4 = h * 64 + 4 * li;
  float4 s = make_float4(0.f, 0.f, 0.f, 0.f);
  const float* xp = x + (size_t)b * T_LEN * ROWLEN + d4;
#pragma unroll 4
  for (int j = 0; j < 64; ++j) {
    int t = tt + 16 * j;
    float4 v = *(const float4*)(xp + (size_t)t * ROWLEN);
    s.x += v.x; s.y += v.y; s.z += v.z; s.w += v.w;
  }
  __shared__ float4 red[16][17];
  red[tt][li] = s;
  __syncthreads();
  for (int st = 8; st > 0; st >>= 1) {
    if (tt < st) {
      float4 o = red[tt + st][li];
      float4 m = red[tt][li];
      m.x += o.x; m.y += o.y; m.z += o.z; m.w += o.w;
      red[tt][li] = m;
    }
    __syncthreads();
  }
  if (tt == 0) {
    float4 m = red[0][li];
    const float inv = 1.0f / 1024.0f;
    m.x *= inv; m.y *= inv; m.z *= inv; m.w *= inv;
    *(float4*)(meang + b * D_CH + d4) = m;
  }
  // Kt[n][k] = (f16) K[k][n] : 64 elements per block
  if (tid < 64) {
    int idx = bid * 64 + tid;
    int n = idx >> 7, k = idx & 127;
    Ktg[idx] = (_Float16)Kmat[k * D_CH + n];
  }
}

// Kernel B: fused softmax + matmul(MFMA f16) + epilogue
__global__ __launch_bounds__(256, 3) void main_kernel(const float* __restrict__ x,
                                                      const float* __restrict__ meang,
                                                      const _Float16* __restrict__ Ktg,
                                                      float* __restrict__ out) {
  __shared__ _Float16 Kt[D_CH * KSTRIDE];   // 34816 B
  __shared__ _Float16 vs[TILE * KSTRIDE];   // 17408 B
  int tid = threadIdx.x;
  // stage Kt (f16, padded stride) once per block
  {
    const uint32_t* kw = (const uint32_t*)Ktg;   // 8192 words
    uint32_t* kl = (uint32_t*)Kt;
#pragma unroll
    for (int i = 0; i < 32; ++i) {
      int widx = tid + i * 256;
      int n = widx >> 6, k2 = widx & 63;         // 64 words per 128-f16 row
      kl[n * (KSTRIDE / 2) + k2] = kw[widx];
    }
  }
  __syncthreads();

  int wave = tid >> 6, lane = tid & 63;
  int hf = lane >> 5, li = lane & 31;
  int c0 = 4 * li;
  int m0 = wave * 16;                            // wave-private 16 rows of the 64-row tile
  int l15 = lane & 15, lg = lane >> 4;
  int abase = (m0 + l15) * KSTRIDE + lg * 8;     // A-frag base in vs
  int bbase = l15 * KSTRIDE + lg * 8;            // B-frag base in Kt

  for (int chunk = blockIdx.x; chunk < NCHUNK; chunk += gridDim.x) {
    int row0 = chunk * TILE;
    int bb = chunk >> 4;                         // 16 chunks per batch (T/TILE = 16)
    const float* mb = meang + bb * D_CH;

    // ---- phase 1: load, exp, softmax, v -> LDS (f16, A-layout) ----
    float4 yb[8], wb[8];
#pragma unroll
    for (int i = 0; i < 8; ++i) {
      size_t base = (size_t)(row0 + m0 + 2 * i + hf) * ROWLEN + c0;
      yb[i] = *(const float4*)(x + base);
      wb[i] = *(const float4*)(x + base + 128);
    }
    float4 mn = *(const float4*)(mb + c0);
#pragma unroll
    for (int i = 0; i < 8; ++i) {
      int rl = m0 + 2 * i + hf;
      int row = row0 + rl;
      float4 e;
      e.x = __expf(wb[i].x); e.y = __expf(wb[i].y);
      e.z = __expf(wb[i].z); e.w = __expf(wb[i].w);
      *(float4*)(out + (size_t)row * ROWLEN + 128 + c0) = e;   // intensity
      float s = e.x + e.y + e.z + e.w;                          // softmax denom (no max-sub; |w|<~7)
      s += __shfl_xor(s, 1, 32);
      s += __shfl_xor(s, 2, 32);
      s += __shfl_xor(s, 4, 32);
      s += __shfl_xor(s, 8, 32);
      s += __shfl_xor(s, 16, 32);
      float rinv = 1.0f / s;
      f16x4 vh;
      vh[0] = (_Float16)(e.x * rinv * (yb[i].x - mn.x));
      vh[1] = (_Float16)(e.y * rinv * (yb[i].y - mn.y));
      vh[2] = (_Float16)(e.z * rinv * (yb[i].z - mn.z));
      vh[3] = (_Float16)(e.w * rinv * (yb[i].w - mn.w));
      *(f16x4*)&vs[rl * KSTRIDE + c0] = vh;
    }

    // ---- phase 2: MFMA 16x16x32 f16 — wave reads only its own 16 rows (no barrier) ----
    f16x8 a[4];
#pragma unroll
    for (int ks = 0; ks < 4; ++ks)
      a[ks] = *(const f16x8*)&vs[abase + ks * 32];
#pragma unroll
    for (int nt = 0; nt < 8; ++nt) {
      f32x4 acc = {0.f, 0.f, 0.f, 0.f};
#pragma unroll
      for (int ks = 0; ks < 4; ++ks) {
        f16x8 bf = *(const f16x8*)&Kt[bbase + nt * 16 * KSTRIDE + ks * 32];
        acc = __builtin_amdgcn_mfma_f32_16x16x32_f16(a[ks], bf, acc, 0, 0, 0);
      }
      // ---- epilogue (C-layout: col = lane&15, row = (lane>>4)*4 + r) ----
      int col = nt * 16 + l15;
      float mcol = mb[col];
#pragma unroll
      for (int r = 0; r < 4; ++r) {
        int row = row0 + m0 + lg * 4 + r;
        size_t ob = (size_t)row * ROWLEN;
        float sm = acc[r] + mcol;                // smooth = matmul + mean
        out[ob + col] = sm;
        out[ob + 256 + col] = x[ob + 256 + col] - sm;   // y_trans
      }
    }
  }
}

extern "C" void kernel_launch(void* const* d_in, const int* in_sizes, int n_in,
                              void* d_out, int out_size, void* d_ws, size_t ws_size,
                              hipStream_t stream) {
  const float* x = (const float*)d_in[0];
  const float* Kmat = (const float*)d_in[1];
  float* out = (float*)d_out;
  float* meang = (float*)d_ws;                          // 128*128 f32 = 64 KB
  _Float16* Ktg = (_Float16*)((char*)d_ws + 65536);     // 128*128 f16 = 32 KB
  prep_kernel<<<256, 256, 0, stream>>>(x, Kmat, meang, Ktg);
  main_kernel<<<1024, 256, 0, stream>>>(x, meang, Ktg, out);
}

// Round 3
// 350.501 us; speedup vs baseline: 1.0150x; 1.0150x over previous
//
#include <hip/hip_runtime.h>
#include <cstdint>

#define D_CH 128
#define T_LEN 1024
#define ROWLEN 384
#define NROWS (128 * 1024)
#define TILE 64
#define NCHUNK (NROWS / TILE)   // 2048
#define VSTR_B 272              // vs row stride bytes (136 f16) — conflict-free b128 reads
#define VS_SLICE (16 * VSTR_B)  // 4352 B per wave
#define EPI_W 132               // epi row stride words (pad 4) — 2-way max banks on scatter
#define EPI_SLICE (16 * EPI_W * 4)  // 8448 B per wave

typedef __attribute__((ext_vector_type(8))) _Float16 f16x8;
typedef __attribute__((ext_vector_type(4))) _Float16 f16x4;
typedef __attribute__((ext_vector_type(4))) float f32x4;

// Kernel A: per-(b,d) mean over T + kernel matrix -> f16 in MFMA-B fragment order.
// Ktg[f], f = ((nt*4+ks)*64 + lane)*8 + j  ->  Kmat[ks*32 + (lane>>4)*8 + j][nt*16 + (lane&15)]
// Total 32 groups * 64 lanes * 8 = 16384 f16 (32 KB).
__global__ __launch_bounds__(256) void prep_kernel(const float* __restrict__ x,
                                                   const float* __restrict__ Kmat,
                                                   float* __restrict__ meang,
                                                   _Float16* __restrict__ Ktg) {
  int bid = blockIdx.x;            // 256 blocks: (b, half-of-D)
  int b = bid >> 1, h = bid & 1;
  int tid = threadIdx.x;
  int li = tid & 15, tt = tid >> 4;      // 16 d-groups x 16 t-slices
  int d4 = h * 64 + 4 * li;
  float4 s = make_float4(0.f, 0.f, 0.f, 0.f);
  const float* xp = x + (size_t)b * T_LEN * ROWLEN + d4;
#pragma unroll 4
  for (int j = 0; j < 64; ++j) {
    int t = tt + 16 * j;
    float4 v = *(const float4*)(xp + (size_t)t * ROWLEN);
    s.x += v.x; s.y += v.y; s.z += v.z; s.w += v.w;
  }
  __shared__ float4 red[16][17];
  red[tt][li] = s;
  __syncthreads();
  for (int st = 8; st > 0; st >>= 1) {
    if (tt < st) {
      float4 o = red[tt + st][li];
      float4 m = red[tt][li];
      m.x += o.x; m.y += o.y; m.z += o.z; m.w += o.w;
      red[tt][li] = m;
    }
    __syncthreads();
  }
  if (tt == 0) {
    float4 m = red[0][li];
    const float inv = 1.0f / 1024.0f;
    m.x *= inv; m.y *= inv; m.z *= inv; m.w *= inv;
    *(float4*)(meang + b * D_CH + d4) = m;
  }
  // fragment-order Kt: 64 f16 per block (16384 total, bijective)
  if (tid < 64) {
    int f = bid * 64 + tid;
    int j = f & 7;
    int lane = (f >> 3) & 63;
    int q = f >> 9;                 // 0..31 = nt*4 + ks
    int ks = q & 3, nt = q >> 2;
    int kk = ks * 32 + (lane >> 4) * 8 + j;
    int nn = nt * 16 + (lane & 15);
    Ktg[f] = (_Float16)Kmat[kk * D_CH + nn];
  }
}

// Kernel B: fused softmax + MFMA matmul + vectorized epilogue.
// B-fragments read straight from frag-order global table (coalesced 1KB/instr, L2-hot 32KB).
// All LDS use is wave-private; ZERO barriers in this kernel.
__global__ __launch_bounds__(256, 3) void main_kernel(const float* __restrict__ x,
                                                      const float* __restrict__ meang,
                                                      const _Float16* __restrict__ Ktg,
                                                      float* __restrict__ out) {
  __shared__ alignas(16) char vsbuf[4 * VS_SLICE];    // 17408 B
  __shared__ alignas(16) char epibuf[4 * EPI_SLICE];  // 33792 B
  int tid = threadIdx.x;
  int wave = tid >> 6, lane = tid & 63;
  int hf = lane >> 5, li = lane & 31;
  int c0 = 4 * li;
  int m0 = wave * 16;                    // wave-private 16 rows of the 64-row tile
  int l15 = lane & 15, lg = lane >> 4;
  char* vslice = vsbuf + wave * VS_SLICE;
  float* epi = (float*)(epibuf + wave * EPI_SLICE);

  int chunk = blockIdx.x;                // grid == NCHUNK: one chunk per block
  int row0 = chunk * TILE;
  int bb = chunk >> 4;                   // T/TILE = 16 chunks per batch
  const float* mb = meang + bb * D_CH;
  float4 mn = *(const float4*)(mb + c0);

  // ---- phase 1: load y,w; exp; store intensity; softmax; v -> LDS (f16 row-major) ----
  float4 yb[8], wb[8];
#pragma unroll
  for (int i = 0; i < 8; ++i) {
    size_t base = (size_t)(row0 + m0 + 2 * i + hf) * ROWLEN + c0;
    yb[i] = *(const float4*)(x + base);
    wb[i] = *(const float4*)(x + base + 128);
  }
#pragma unroll
  for (int i = 0; i < 8; ++i) {
    int lr = 2 * i + hf;
    int row = row0 + m0 + lr;
    float4 e;
    e.x = __expf(wb[i].x); e.y = __expf(wb[i].y);
    e.z = __expf(wb[i].z); e.w = __expf(wb[i].w);
    *(float4*)(out + (size_t)row * ROWLEN + 128 + c0) = e;   // intensity
    float s = e.x + e.y + e.z + e.w;                          // |w| small: no max-sub needed
    s += __shfl_xor(s, 1, 32);
    s += __shfl_xor(s, 2, 32);
    s += __shfl_xor(s, 4, 32);
    s += __shfl_xor(s, 8, 32);
    s += __shfl_xor(s, 16, 32);
    float rinv = 1.0f / s;
    f16x4 vh;
    vh[0] = (_Float16)(e.x * rinv * (yb[i].x - mn.x));
    vh[1] = (_Float16)(e.y * rinv * (yb[i].y - mn.y));
    vh[2] = (_Float16)(e.z * rinv * (yb[i].z - mn.z));
    vh[3] = (_Float16)(e.w * rinv * (yb[i].w - mn.w));
    *(f16x4*)(vslice + lr * VSTR_B + li * 8) = vh;
  }

  // ---- phase 2: A-frags from LDS, B-frags from global frag-order table ----
  f16x8 a[4];
#pragma unroll
  for (int ks = 0; ks < 4; ++ks)
    a[ks] = *(const f16x8*)(vslice + l15 * VSTR_B + ks * 64 + lg * 16);
  f32x4 acc[8];
#pragma unroll
  for (int nt = 0; nt < 8; ++nt) {
    acc[nt] = (f32x4){0.f, 0.f, 0.f, 0.f};
#pragma unroll
    for (int ks = 0; ks < 4; ++ks) {
      f16x8 bf = *(const f16x8*)&Ktg[((nt * 4 + ks) * 64 + lane) * 8];
      acc[nt] = __builtin_amdgcn_mfma_f32_16x16x32_f16(a[ks], bf, acc[nt], 0, 0, 0);
    }
  }

  // ---- epilogue: C-layout -> LDS pane (2-way max banks), read back row-major float4 ----
#pragma unroll
  for (int nt = 0; nt < 8; ++nt)
#pragma unroll
    for (int r = 0; r < 4; ++r)
      epi[(lg * 4 + r) * EPI_W + nt * 16 + l15] = acc[nt][r];

#pragma unroll
  for (int i = 0; i < 8; ++i) {
    int lr = 2 * i + hf;
    size_t ob = (size_t)(row0 + m0 + lr) * ROWLEN;
    float4 sm4 = *(const float4*)&epi[lr * EPI_W + c0];
    sm4.x += mn.x; sm4.y += mn.y; sm4.z += mn.z; sm4.w += mn.w;
    float4 yo = *(const float4*)(x + ob + 256 + c0);
    *(float4*)(out + ob + c0) = sm4;                          // smooth
    float4 yt;
    yt.x = yo.x - sm4.x; yt.y = yo.y - sm4.y;
    yt.z = yo.z - sm4.z; yt.w = yo.w - sm4.w;
    *(float4*)(out + ob + 256 + c0) = yt;                     // y_trans
  }
}

extern "C" void kernel_launch(void* const* d_in, const int* in_sizes, int n_in,
                              void* d_out, int out_size, void* d_ws, size_t ws_size,
                              hipStream_t stream) {
  const float* x = (const float*)d_in[0];
  const float* Kmat = (const float*)d_in[1];
  float* out = (float*)d_out;
  float* meang = (float*)d_ws;                          // 128*128 f32 = 64 KB
  _Float16* Ktg = (_Float16*)((char*)d_ws + 65536);     // 16384 f16 = 32 KB (frag order)
  prep_kernel<<<256, 256, 0, stream>>>(x, Kmat, meang, Ktg);
  main_kernel<<<NCHUNK, 256, 0, stream>>>(x, meang, Ktg, out);
}